// Round 2
// baseline (255871.777 us; speedup 1.0000x reference)
//
#include <hip/hip_runtime.h>
#include <hip/hip_bf16.h>
#include <stdint.h>

#define T_SEQ 8192
#define E_IN  512
#define H_DIM 1024
#define FH    4096   // 4*H
#define H2    2048   // 2*H
#define NLAB  5
#define NEGV  (-10000.0f)

typedef __attribute__((ext_vector_type(8))) short bf16x8;
typedef __attribute__((ext_vector_type(4))) float f32x4;

__device__ __forceinline__ uint32_t f2bf(float f) {
  uint32_t x = __float_as_uint(f);
  return (x + 0x7FFFu + ((x >> 16) & 1u)) >> 16;   // RNE f32->bf16
}
__device__ __forceinline__ uint32_t pack2bf(float lo, float hi) {
  return f2bf(lo) | (f2bf(hi) << 16);
}
__device__ __forceinline__ float bf2f(uint32_t b) {
  return __uint_as_float(b << 16);
}
__device__ __forceinline__ float fsig(float x) { return 1.0f / (1.0f + __expf(-x)); }
__device__ __forceinline__ float ftanh(float x) {
  float ax = fabsf(x);
  float e = __expf(-2.0f * ax);
  float t = (1.0f - e) / (1.0f + e);
  return copysignf(t, x);
}

// ---------------------------------------------------------------- bias prep
__global__ void bias_kernel(const float* bi0, const float* bh0,
                            const float* bi0r, const float* bh0r,
                            const float* bi1, const float* bh1,
                            const float* bi1r, const float* bh1r,
                            float* bsum) {
  int i = blockIdx.x * blockDim.x + threadIdx.x;  // 0..16383
  int d = i >> 12, j = i & 4095;
  const float *a, *b;
  switch (d) {
    case 0:  a = bi0;  b = bh0;  break;
    case 1:  a = bi0r; b = bh0r; break;
    case 2:  a = bi1;  b = bh1;  break;
    default: a = bi1r; b = bh1r; break;
  }
  bsum[i] = a[j] + b[j];
}

// ---------------------------------------------------------------- xg GEMM
// C[8192][4096](bf16) = A[8192][K] x Bt[4096][K]^T + bias[4096]
// A is f32 (hours) or bf16 (h0seq); Bt (w_ih) is f32, converted while staging.
template <bool AF32>
__global__ __launch_bounds__(256) void gemm_xg(const void* Aptr, const float* Bt,
                                               const float* bias, uint16_t* C, int K) {
  const int m0 = blockIdx.x * 128;
  const int n0 = blockIdx.y * 128;
  __shared__ uint32_t As[128 * 20];  // 128 x 40 bf16 (32 + 8 pad)
  __shared__ uint32_t Bs[128 * 20];
  const int tid  = threadIdx.x;
  const int lane = tid & 63;
  const int wave = tid >> 6;
  const int wr = wave >> 1, wc = wave & 1;
  const int row = tid >> 1;   // 0..127
  const int seg = tid & 1;    // 16-element segment

  f32x4 acc[4][4];
#pragma unroll
  for (int i = 0; i < 4; ++i)
#pragma unroll
    for (int j = 0; j < 4; ++j)
      acc[i][j] = (f32x4){0.0f, 0.0f, 0.0f, 0.0f};

  const int nk = K / 32;
  for (int kk = 0; kk < nk; ++kk) {
    const int k0 = kk * 32;
    uint32_t* dst = &As[row * 20 + seg * 8];
    if (AF32) {
      const float4* src = (const float4*)((const float*)Aptr + (size_t)(m0 + row) * K + k0 + seg * 16);
      uint32_t w[8];
#pragma unroll
      for (int u = 0; u < 4; ++u) {
        float4 v = src[u];
        w[2 * u]     = pack2bf(v.x, v.y);
        w[2 * u + 1] = pack2bf(v.z, v.w);
      }
      ((uint4*)dst)[0] = make_uint4(w[0], w[1], w[2], w[3]);
      ((uint4*)dst)[1] = make_uint4(w[4], w[5], w[6], w[7]);
    } else {
      const uint4* src = (const uint4*)((const uint16_t*)Aptr + (size_t)(m0 + row) * K + k0 + seg * 16);
      ((uint4*)dst)[0] = src[0];
      ((uint4*)dst)[1] = src[1];
    }
    {
      const float4* src = (const float4*)(Bt + (size_t)(n0 + row) * K + k0 + seg * 16);
      uint32_t w[8];
#pragma unroll
      for (int u = 0; u < 4; ++u) {
        float4 v = src[u];
        w[2 * u]     = pack2bf(v.x, v.y);
        w[2 * u + 1] = pack2bf(v.z, v.w);
      }
      uint32_t* dstb = &Bs[row * 20 + seg * 8];
      ((uint4*)dstb)[0] = make_uint4(w[0], w[1], w[2], w[3]);
      ((uint4*)dstb)[1] = make_uint4(w[4], w[5], w[6], w[7]);
    }
    __syncthreads();

    const int mfrag = lane & 15, kq = lane >> 4;
    bf16x8 af[4], bfr[4];
#pragma unroll
    for (int i = 0; i < 4; ++i) {
      af[i]  = *(const bf16x8*)&As[(wr * 64 + i * 16 + mfrag) * 20 + kq * 4];
      bfr[i] = *(const bf16x8*)&Bs[(wc * 64 + i * 16 + mfrag) * 20 + kq * 4];
    }
#pragma unroll
    for (int i = 0; i < 4; ++i)
#pragma unroll
      for (int j = 0; j < 4; ++j)
        acc[i][j] = __builtin_amdgcn_mfma_f32_16x16x32_bf16(af[i], bfr[j], acc[i][j], 0, 0, 0);
    __syncthreads();
  }

  // epilogue: C/D layout col=lane&15 (B/n index), row=(lane>>4)*4+reg (A/m index)
  const int colq = lane & 15, rowq = lane >> 4;
#pragma unroll
  for (int j = 0; j < 4; ++j) {
    const int col = n0 + wc * 64 + j * 16 + colq;
    const float bv = bias[col];
#pragma unroll
    for (int i = 0; i < 4; ++i) {
#pragma unroll
      for (int r = 0; r < 4; ++r) {
        const int rrow = m0 + wr * 64 + i * 16 + rowq * 4 + r;
        C[(size_t)rrow * FH + col] = (uint16_t)f2bf(acc[i][j][r] + bv);
      }
    }
  }
}

// ---------------------------------------------------------------- LSTM layer
// 128 persistent WGs: dir = bid&1 (fwd/bwd), g = bid>>1 owns h-indices [16g,16g+16).
// W_hh slice (64 gate-rows x 1024) lives in VGPRs (f32).
// Exchange protocol (lag-tolerant):
//   data:  hpub[2][1024] f32, parity double-buffered by step (h_s -> buf s&1)
//   flags: flags[64] int, producer g release-stores s+1 after its 16 data words
//   poll:  each wave polls all 64 flags (lane l -> flags[l]) for >= s (signed,
//          so 0xAA poison never false-passes), acquire; then reads buf (s-1)&1
//          with agent-scope atomic loads (bypass stale L1/L2).
// Safety: a producer can pass its step-(s+1) poll only after EVERY WG published
// flag s+1, i.e. after every WG finished reading buf (s-1)&1 — which is the
// buffer it would overwrite at step s+2. So lag up to a full step is safe.
__global__ __launch_bounds__(256, 1) void lstm_layer(
    const float* __restrict__ whh_f, const float* __restrict__ whh_b,
    const uint16_t* __restrict__ xg_f, const uint16_t* __restrict__ xg_b,
    uint32_t* hpub_f, uint32_t* hpub_b, int* flags_f, int* flags_b,
    uint16_t* __restrict__ hseq) {
  const int bid = blockIdx.x;
  const int dir = bid & 1;
  const int g   = bid >> 1;      // 0..63
  const int hb  = g * 16;
  const int tid = threadIdx.x;
  const int jj  = tid & 15;      // h-index within slice
  const int kc  = tid >> 4;      // k-chunk (64 elems each), 0..15
  const int lane = tid & 63;

  const float*    whh   = dir ? whh_b : whh_f;
  const uint16_t* xg    = dir ? xg_b : xg_f;
  uint32_t*       hpub  = dir ? hpub_b : hpub_f;
  int*            flags = dir ? flags_b : flags_f;
  const int colbase     = dir ? H_DIM : 0;

  __shared__ __align__(16) float h_lds[H_DIM];
  __shared__ __align__(16) float part2[4][16][4];

  // load W_hh slice into registers: Wr[q][i] = W_hh[q*1024 + hb + jj][kc*64 + i]
  float Wr[4][64];
#pragma unroll
  for (int q = 0; q < 4; ++q) {
    const float4* wrow = (const float4*)(whh + (size_t)(q * H_DIM + hb + jj) * H_DIM + kc * 64);
#pragma unroll
    for (int i4 = 0; i4 < 16; ++i4) {
      float4 v = wrow[i4];
      Wr[q][i4 * 4 + 0] = v.x; Wr[q][i4 * 4 + 1] = v.y;
      Wr[q][i4 * 4 + 2] = v.z; Wr[q][i4 * 4 + 3] = v.w;
    }
  }

  const int gjj = tid & 15;
  const int gq  = tid >> 4;                    // gate idx when tid<64
  const int growrow = gq * H_DIM + hb + gjj;   // row in [0,4096) when tid<64

  float cstate = 0.0f;  // threads 0..15 hold c for h-index hb+tid

  for (int s = 0; s < T_SEQ; ++s) {
    const int t = dir ? (T_SEQ - 1 - s) : s;

    float xgv = 0.0f;
    if (tid < 64) xgv = bf2f(xg[(size_t)t * FH + growrow]);  // prefetch

    if (s == 0) {
      ((float4*)h_lds)[tid] = make_float4(0.f, 0.f, 0.f, 0.f);
    } else {
      // poll: every wave checks all 64 producer flags (lane l -> flags[l])
      for (;;) {
        int fl = (int)__hip_atomic_load(&flags[lane], __ATOMIC_ACQUIRE,
                                        __HIP_MEMORY_SCOPE_AGENT);
        if (__all(fl >= s)) break;
        __builtin_amdgcn_s_sleep(2);
      }
      const unsigned long long* hp64 =
          (const unsigned long long*)(hpub + (((s - 1) & 1) ? H_DIM : 0));
      unsigned long long a = __hip_atomic_load((unsigned long long*)&hp64[2 * tid],
                                               __ATOMIC_RELAXED, __HIP_MEMORY_SCOPE_AGENT);
      unsigned long long b = __hip_atomic_load((unsigned long long*)&hp64[2 * tid + 1],
                                               __ATOMIC_RELAXED, __HIP_MEMORY_SCOPE_AGENT);
      ((float4*)h_lds)[tid] = make_float4(
          __uint_as_float((uint32_t)a), __uint_as_float((uint32_t)(a >> 32)),
          __uint_as_float((uint32_t)b), __uint_as_float((uint32_t)(b >> 32)));
    }
    __syncthreads();  // h_lds ready

    // dot: 4 gate rows (q=0..3) over this thread's 64-wide k-chunk
    float a0 = 0.f, a1 = 0.f, a2 = 0.f, a3 = 0.f;
#pragma unroll
    for (int ii = 0; ii < 16; ++ii) {
      float4 h4 = ((const float4*)h_lds)[kc * 16 + ii];
      a0 += Wr[0][ii * 4 + 0] * h4.x; a0 += Wr[0][ii * 4 + 1] * h4.y;
      a0 += Wr[0][ii * 4 + 2] * h4.z; a0 += Wr[0][ii * 4 + 3] * h4.w;
      a1 += Wr[1][ii * 4 + 0] * h4.x; a1 += Wr[1][ii * 4 + 1] * h4.y;
      a1 += Wr[1][ii * 4 + 2] * h4.z; a1 += Wr[1][ii * 4 + 3] * h4.w;
      a2 += Wr[2][ii * 4 + 0] * h4.x; a2 += Wr[2][ii * 4 + 1] * h4.y;
      a2 += Wr[2][ii * 4 + 2] * h4.z; a2 += Wr[2][ii * 4 + 3] * h4.w;
      a3 += Wr[3][ii * 4 + 0] * h4.x; a3 += Wr[3][ii * 4 + 1] * h4.y;
      a3 += Wr[3][ii * 4 + 2] * h4.z; a3 += Wr[3][ii * 4 + 3] * h4.w;
    }
    // in-wave reduce over the wave's 4 k-chunks (lanes differing in bits 4,5)
    a0 += __shfl_xor(a0, 16); a1 += __shfl_xor(a1, 16);
    a2 += __shfl_xor(a2, 16); a3 += __shfl_xor(a3, 16);
    a0 += __shfl_xor(a0, 32); a1 += __shfl_xor(a1, 32);
    a2 += __shfl_xor(a2, 32); a3 += __shfl_xor(a3, 32);
    if (lane < 16)
      *(float4*)&part2[tid >> 6][jj][0] = make_float4(a0, a1, a2, a3);
    __syncthreads();  // part2 ready

    if (tid < 64) {
      float gval = part2[0][gjj][gq] + part2[1][gjj][gq] +
                   part2[2][gjj][gq] + part2[3][gjj][gq] + xgv;
      // gather 4 gates of h-index gjj (lanes gjj, +16, +32, +48 of wave 0)
      float gi = gval;
      float gf = __shfl(gval, gjj + 16);
      float gg = __shfl(gval, gjj + 32);
      float go = __shfl(gval, gjj + 48);
      if (gq == 0) {
        float i_s = fsig(gi), f_s = fsig(gf), g_t = ftanh(gg), o_s = fsig(go);
        cstate = f_s * cstate + i_s * g_t;
        float h = o_s * ftanh(cstate);
        __hip_atomic_store(&hpub[(s & 1) * H_DIM + hb + gjj], __float_as_uint(h),
                           __ATOMIC_RELAXED, __HIP_MEMORY_SCOPE_AGENT);
        hseq[(size_t)t * H2 + colbase + hb + gjj] = (uint16_t)f2bf(h);
        if (gjj == 0)
          __hip_atomic_store(&flags[g], s + 1, __ATOMIC_RELEASE,
                             __HIP_MEMORY_SCOPE_AGENT);
      }
    }
    // no trailing barrier: next-step h_lds writes are gated by the poll, which
    // requires this WG's own flag (published after all this step's LDS reads).
  }
}

// ---------------------------------------------------------------- feats
// feats[t][l] = h1[t,:] . w_out[l,:] + b_out[l];  one wave per row.
__global__ __launch_bounds__(256) void feats_kernel(const uint16_t* __restrict__ h1,
                                                    const float* __restrict__ wout,
                                                    const float* __restrict__ bout,
                                                    float* __restrict__ feats) {
  const int lane = threadIdx.x & 63;
  const int wid  = (blockIdx.x * blockDim.x + threadIdx.x) >> 6;
  const int nwaves = (gridDim.x * blockDim.x) >> 6;

  float wreg[5][32];
#pragma unroll
  for (int j = 0; j < 5; ++j) {
    const float4* src = (const float4*)(wout + j * H2 + lane * 32);
#pragma unroll
    for (int u = 0; u < 8; ++u) {
      float4 v = src[u];
      wreg[j][u * 4 + 0] = v.x; wreg[j][u * 4 + 1] = v.y;
      wreg[j][u * 4 + 2] = v.z; wreg[j][u * 4 + 3] = v.w;
    }
  }
  for (int t = wid; t < T_SEQ; t += nwaves) {
    const uint32_t* hrow = (const uint32_t*)(h1 + (size_t)t * H2) + lane * 16;
    float acc[5] = {0.f, 0.f, 0.f, 0.f, 0.f};
#pragma unroll
    for (int u = 0; u < 16; ++u) {
      uint32_t w2 = hrow[u];
      float hlo = __uint_as_float(w2 << 16);
      float hhi = __uint_as_float(w2 & 0xFFFF0000u);
#pragma unroll
      for (int j = 0; j < 5; ++j)
        acc[j] += wreg[j][u * 2] * hlo + wreg[j][u * 2 + 1] * hhi;
    }
#pragma unroll
    for (int off = 32; off >= 1; off >>= 1)
#pragma unroll
      for (int j = 0; j < 5; ++j)
        acc[j] += __shfl_xor(acc[j], off);
    if (lane < 5) feats[t * NLAB + lane] = acc[lane] + bout[lane];
  }
}

// ---------------------------------------------------------------- Viterbi
// Parallel max-plus scan (chunks of 32 per thread), bps in LDS, pointer-jump backtrack.
__global__ __launch_bounds__(256) void viterbi_kernel(const float* __restrict__ feats,
                                                      const float* __restrict__ trans,
                                                      float* __restrict__ out) {
  __shared__ float scanM[256][26];
  __shared__ uint16_t bpsL[T_SEQ];
  __shared__ int bestL;
  const int tid = threadIdx.x;

  float tr[5][5];
#pragma unroll
  for (int n = 0; n < 5; ++n)
#pragma unroll
    for (int p = 0; p < 5; ++p) tr[n][p] = trans[n * 5 + p];

  // phase 1: per-thread chunk composite C = M[t_hi] (x) ... (x) M[t_lo]
  float C[5][5];
  {
    const int t0 = tid * 32;
    const float* f = feats + (size_t)t0 * 5;
#pragma unroll
    for (int n = 0; n < 5; ++n)
#pragma unroll
      for (int p = 0; p < 5; ++p) C[n][p] = tr[n][p] + f[n];
    for (int t = 1; t < 32; ++t) {
      const float* ft = feats + (size_t)(t0 + t) * 5;
      float Nw[5][5];
#pragma unroll
      for (int n = 0; n < 5; ++n) {
#pragma unroll
        for (int p = 0; p < 5; ++p) {
          float m = tr[n][0] + C[0][p];
#pragma unroll
          for (int k = 1; k < 5; ++k) m = fmaxf(m, tr[n][k] + C[k][p]);
          Nw[n][p] = m + ft[n];
        }
      }
#pragma unroll
      for (int n = 0; n < 5; ++n)
#pragma unroll
        for (int p = 0; p < 5; ++p) C[n][p] = Nw[n][p];
    }
#pragma unroll
    for (int n = 0; n < 5; ++n)
#pragma unroll
      for (int p = 0; p < 5; ++p) scanM[tid][n * 5 + p] = C[n][p];
  }
  __syncthreads();

  // phase 2: in-place Hillis-Steele inclusive scan (later (x) earlier)
  for (int d = 1; d < 256; d <<= 1) {
    float A[5][5], B[5][5];
    const bool has = (tid >= d);
#pragma unroll
    for (int n = 0; n < 5; ++n)
#pragma unroll
      for (int p = 0; p < 5; ++p) A[n][p] = scanM[tid][n * 5 + p];
    if (has) {
#pragma unroll
      for (int n = 0; n < 5; ++n)
#pragma unroll
        for (int p = 0; p < 5; ++p) B[n][p] = scanM[tid - d][n * 5 + p];
    }
    __syncthreads();
    if (has) {
#pragma unroll
      for (int n = 0; n < 5; ++n) {
#pragma unroll
        for (int p = 0; p < 5; ++p) {
          float m = A[n][0] + B[0][p];
#pragma unroll
          for (int k = 1; k < 5; ++k) m = fmaxf(m, A[n][k] + B[k][p]);
          scanM[tid][n * 5 + p] = m;
        }
      }
    }
    __syncthreads();
  }

  // base vector for this chunk: fv = P_{tid-1} (x) init  (init = NEG except [3]=0)
  float fv[5];
  if (tid == 0) {
#pragma unroll
    for (int n = 0; n < 5; ++n) fv[n] = (n == 3) ? 0.0f : NEGV;
  } else {
#pragma unroll
    for (int n = 0; n < 5; ++n) {
      float m = scanM[tid - 1][n * 5 + 3];
#pragma unroll
      for (int p = 0; p < 5; ++p)
        if (p != 3) m = fmaxf(m, scanM[tid - 1][n * 5 + p] + NEGV);
      fv[n] = m;
    }
  }

  // phase 3: exact sequential semantics within chunk; emit backpointers
  {
    const int t0 = tid * 32;
    for (int t = 0; t < 32; ++t) {
      const float* ft = feats + (size_t)(t0 + t) * 5;
      float nf[5];
      uint32_t bits = 0;
#pragma unroll
      for (int n = 0; n < 5; ++n) {
        float m = tr[n][0] + fv[0];
        int arg = 0;
#pragma unroll
        for (int p = 1; p < 5; ++p) {
          float s2 = tr[n][p] + fv[p];
          if (s2 > m) { m = s2; arg = p; }
        }
        nf[n] = m + ft[n];
        bits |= (uint32_t)arg << (3 * n);
      }
      bpsL[t0 + t] = (uint16_t)bits;
#pragma unroll
      for (int n = 0; n < 5; ++n) fv[n] = nf[n];
    }
    if (tid == 255) {
      float m = fv[0] + tr[4][0];
      int arg = 0;
#pragma unroll
      for (int p = 1; p < 5; ++p) {
        float s2 = fv[p] + tr[4][p];
        if (s2 > m) { m = s2; arg = p; }
      }
      out[0] = m;       // score
      bestL = arg;
    }
  }
  __syncthreads();

  // phase 4: suffix composition S[t] = J[t] o J[t+1] o ... via pointer jumping
  for (int d = 1; d < T_SEQ; d <<= 1) {
    uint32_t own[32], par[32];
#pragma unroll
    for (int k = 0; k < 32; ++k) {
      int t = tid + k * 256;
      own[k] = bpsL[t];
      par[k] = (t + d < T_SEQ) ? (uint32_t)bpsL[t + d] : 0u;
    }
    __syncthreads();
#pragma unroll
    for (int k = 0; k < 32; ++k) {
      int t = tid + k * 256;
      if (t + d < T_SEQ) {
        uint32_t fmp = own[k], gmp = par[k], r = 0;
#pragma unroll
        for (int x = 0; x < 5; ++x) {
          uint32_t j = (gmp >> (3 * x)) & 7u;
          uint32_t v = (fmp >> (3 * j)) & 7u;
          r |= v << (3 * x);
        }
        bpsL[t] = (uint16_t)r;
      }
    }
    __syncthreads();
  }

  const int best = bestL;
  for (int k = 0; k < 32; ++k) {
    int t = tid + k * 256;
    int lbl = (t == T_SEQ - 1) ? best : (int)((bpsL[t + 1] >> (3 * best)) & 7u);
    out[1 + t] = (float)lbl;
  }
}

// ---------------------------------------------------------------- launcher
extern "C" void kernel_launch(void* const* d_in, const int* in_sizes, int n_in,
                              void* d_out, int out_size, void* d_ws, size_t ws_size,
                              hipStream_t stream) {
  const float* hours     = (const float*)d_in[0];
  const float* w_ih_l0   = (const float*)d_in[1];
  const float* w_hh_l0   = (const float*)d_in[2];
  const float* b_ih_l0   = (const float*)d_in[3];
  const float* b_hh_l0   = (const float*)d_in[4];
  const float* w_ih_l0r  = (const float*)d_in[5];
  const float* w_hh_l0r  = (const float*)d_in[6];
  const float* b_ih_l0r  = (const float*)d_in[7];
  const float* b_hh_l0r  = (const float*)d_in[8];
  const float* w_ih_l1   = (const float*)d_in[9];
  const float* w_hh_l1   = (const float*)d_in[10];
  const float* b_ih_l1   = (const float*)d_in[11];
  const float* b_hh_l1   = (const float*)d_in[12];
  const float* w_ih_l1r  = (const float*)d_in[13];
  const float* w_hh_l1r  = (const float*)d_in[14];
  const float* b_ih_l1r  = (const float*)d_in[15];
  const float* b_hh_l1r  = (const float*)d_in[16];
  const float* w_out     = (const float*)d_in[17];
  const float* b_out     = (const float*)d_in[18];
  const float* transitions = (const float*)d_in[19];
  float* out = (float*)d_out;

  // ws layout (peak ~160.6 MB): h1seq aliases h0seq (h0 is dead once the
  // layer-1 gemms have consumed it; layer-1 lstm reads only xgf/xgb).
  char* ws = (char*)d_ws;
  size_t off = 0;
  auto alloc = [&](size_t bytes) -> void* {
    void* p = ws + off;
    off += (bytes + 255) & ~(size_t)255;
    return p;
  };
  uint16_t* xgf   = (uint16_t*)alloc((size_t)T_SEQ * FH * 2);   // 64 MB (reused for layer 1)
  uint16_t* xgb   = (uint16_t*)alloc((size_t)T_SEQ * FH * 2);   // 64 MB
  uint16_t* h0seq = (uint16_t*)alloc((size_t)T_SEQ * H2 * 2);   // 32 MB (h1seq aliases this)
  uint16_t* h1seq = h0seq;
  float*    bsum  = (float*)alloc((size_t)4 * FH * 4);
  uint32_t* hpub  = (uint32_t*)alloc((size_t)2 * 2 * 2 * H_DIM * 4); // layer x dir x parity
  int*      flags = (int*)alloc((size_t)2 * 2 * 64 * 4);            // layer x dir x 64
  float*    feats = (float*)alloc((size_t)T_SEQ * NLAB * 4);
  (void)ws_size; (void)in_sizes; (void)n_in; (void)out_size;

  bias_kernel<<<64, 256, 0, stream>>>(b_ih_l0, b_hh_l0, b_ih_l0r, b_hh_l0r,
                                      b_ih_l1, b_hh_l1, b_ih_l1r, b_hh_l1r, bsum);
  dim3 gg(64, 32);
  gemm_xg<true><<<gg, 256, 0, stream>>>(hours, w_ih_l0,  bsum + 0 * FH, xgf, E_IN);
  gemm_xg<true><<<gg, 256, 0, stream>>>(hours, w_ih_l0r, bsum + 1 * FH, xgb, E_IN);
  lstm_layer<<<128, 256, 0, stream>>>(w_hh_l0, w_hh_l0r, xgf, xgb,
                                      hpub + 0, hpub + 2048, flags + 0, flags + 64,
                                      h0seq);
  gemm_xg<false><<<gg, 256, 0, stream>>>(h0seq, w_ih_l1,  bsum + 2 * FH, xgf, H2);
  gemm_xg<false><<<gg, 256, 0, stream>>>(h0seq, w_ih_l1r, bsum + 3 * FH, xgb, H2);
  lstm_layer<<<128, 256, 0, stream>>>(w_hh_l1, w_hh_l1r, xgf, xgb,
                                      hpub + 4096, hpub + 6144, flags + 128, flags + 192,
                                      h1seq);
  feats_kernel<<<128, 256, 0, stream>>>(h1seq, w_out, b_out, feats);
  viterbi_kernel<<<1, 256, 0, stream>>>(feats, transitions, out);
}

// Round 3
// 30543.811 us; speedup vs baseline: 8.3772x; 8.3772x over previous
//
#include <hip/hip_runtime.h>
#include <hip/hip_bf16.h>
#include <stdint.h>

#define T_SEQ 8192
#define E_IN  512
#define H_DIM 1024
#define FH    4096   // 4*H
#define H2    2048   // 2*H
#define NLAB  5
#define NEGV  (-10000.0f)

typedef __attribute__((ext_vector_type(8))) short bf16x8;
typedef __attribute__((ext_vector_type(4))) float f32x4;

__device__ __forceinline__ uint32_t f2bf(float f) {
  uint32_t x = __float_as_uint(f);
  return (x + 0x7FFFu + ((x >> 16) & 1u)) >> 16;   // RNE f32->bf16
}
__device__ __forceinline__ uint32_t pack2bf(float lo, float hi) {
  return f2bf(lo) | (f2bf(hi) << 16);
}
__device__ __forceinline__ float bf2f(uint32_t b) {
  return __uint_as_float(b << 16);
}
__device__ __forceinline__ float fsig(float x) { return 1.0f / (1.0f + __expf(-x)); }
__device__ __forceinline__ float ftanh(float x) {
  float ax = fabsf(x);
  float e = __expf(-2.0f * ax);
  float t = (1.0f - e) / (1.0f + e);
  return copysignf(t, x);
}

// ---------------------------------------------------------------- bias prep
__global__ void bias_kernel(const float* bi0, const float* bh0,
                            const float* bi0r, const float* bh0r,
                            const float* bi1, const float* bh1,
                            const float* bi1r, const float* bh1r,
                            float* bsum) {
  int i = blockIdx.x * blockDim.x + threadIdx.x;  // 0..16383
  int d = i >> 12, j = i & 4095;
  const float *a, *b;
  switch (d) {
    case 0:  a = bi0;  b = bh0;  break;
    case 1:  a = bi0r; b = bh0r; break;
    case 2:  a = bi1;  b = bh1;  break;
    default: a = bi1r; b = bh1r; break;
  }
  bsum[i] = a[j] + b[j];
}

// ---------------------------------------------------------------- xg GEMM
// C[8192][4096](bf16) = A[8192][K] x Bt[4096][K]^T + bias[4096], written in
// PERMUTED column order: pcol = ((col&1023)>>4)*64 + (col>>10)*16 + (col&15),
// so LSTM WG g reads its 64 gate values as one contiguous 128 B line.
template <bool AF32>
__global__ __launch_bounds__(256) void gemm_xg(const void* Aptr, const float* Bt,
                                               const float* bias, uint16_t* C, int K) {
  const int m0 = blockIdx.x * 128;
  const int n0 = blockIdx.y * 128;
  __shared__ uint32_t As[128 * 20];  // 128 x 40 bf16 (32 + 8 pad)
  __shared__ uint32_t Bs[128 * 20];
  const int tid  = threadIdx.x;
  const int lane = tid & 63;
  const int wave = tid >> 6;
  const int wr = wave >> 1, wc = wave & 1;
  const int row = tid >> 1;   // 0..127
  const int seg = tid & 1;    // 16-element segment

  f32x4 acc[4][4];
#pragma unroll
  for (int i = 0; i < 4; ++i)
#pragma unroll
    for (int j = 0; j < 4; ++j)
      acc[i][j] = (f32x4){0.0f, 0.0f, 0.0f, 0.0f};

  const int nk = K / 32;
  for (int kk = 0; kk < nk; ++kk) {
    const int k0 = kk * 32;
    uint32_t* dst = &As[row * 20 + seg * 8];
    if (AF32) {
      const float4* src = (const float4*)((const float*)Aptr + (size_t)(m0 + row) * K + k0 + seg * 16);
      uint32_t w[8];
#pragma unroll
      for (int u = 0; u < 4; ++u) {
        float4 v = src[u];
        w[2 * u]     = pack2bf(v.x, v.y);
        w[2 * u + 1] = pack2bf(v.z, v.w);
      }
      ((uint4*)dst)[0] = make_uint4(w[0], w[1], w[2], w[3]);
      ((uint4*)dst)[1] = make_uint4(w[4], w[5], w[6], w[7]);
    } else {
      const uint4* src = (const uint4*)((const uint16_t*)Aptr + (size_t)(m0 + row) * K + k0 + seg * 16);
      ((uint4*)dst)[0] = src[0];
      ((uint4*)dst)[1] = src[1];
    }
    {
      const float4* src = (const float4*)(Bt + (size_t)(n0 + row) * K + k0 + seg * 16);
      uint32_t w[8];
#pragma unroll
      for (int u = 0; u < 4; ++u) {
        float4 v = src[u];
        w[2 * u]     = pack2bf(v.x, v.y);
        w[2 * u + 1] = pack2bf(v.z, v.w);
      }
      uint32_t* dstb = &Bs[row * 20 + seg * 8];
      ((uint4*)dstb)[0] = make_uint4(w[0], w[1], w[2], w[3]);
      ((uint4*)dstb)[1] = make_uint4(w[4], w[5], w[6], w[7]);
    }
    __syncthreads();

    const int mfrag = lane & 15, kq = lane >> 4;
    bf16x8 af[4], bfr[4];
#pragma unroll
    for (int i = 0; i < 4; ++i) {
      af[i]  = *(const bf16x8*)&As[(wr * 64 + i * 16 + mfrag) * 20 + kq * 4];
      bfr[i] = *(const bf16x8*)&Bs[(wc * 64 + i * 16 + mfrag) * 20 + kq * 4];
    }
#pragma unroll
    for (int i = 0; i < 4; ++i)
#pragma unroll
      for (int j = 0; j < 4; ++j)
        acc[i][j] = __builtin_amdgcn_mfma_f32_16x16x32_bf16(af[i], bfr[j], acc[i][j], 0, 0, 0);
    __syncthreads();
  }

  // epilogue: C/D layout col=lane&15 (B/n index), row=(lane>>4)*4+reg (A/m index)
  const int colq = lane & 15, rowq = lane >> 4;
#pragma unroll
  for (int j = 0; j < 4; ++j) {
    const int col = n0 + wc * 64 + j * 16 + colq;
    const float bv = bias[col];
    const int pcol = ((col & 1023) >> 4) * 64 + (col >> 10) * 16 + (col & 15);
#pragma unroll
    for (int i = 0; i < 4; ++i) {
#pragma unroll
      for (int r = 0; r < 4; ++r) {
        const int rrow = m0 + wr * 64 + i * 16 + rowq * 4 + r;
        C[(size_t)rrow * FH + pcol] = (uint16_t)f2bf(acc[i][j][r] + bv);
      }
    }
  }
}

// ---------------------------------------------------------------- LSTM layer
// 128 persistent WGs x 512 thr: dir = bid&1, g = bid>>1 owns h[16g..16g+16).
// W_hh slice (64 gate-rows x 1024) in VGPRs: 128 f32/thread (no spill).
// Exchange: SINGLE-HOP self-tagged words, parity double-buffered.
//   word = (step<<16) | bf16(h), relaxed agent atomics only.
//   step s publishes h_s into hpub[s&1][1024]; step s+1 polls buf[s&1] for
//   tag==s. Safety: WG P writes step s only after seeing ALL tag-(s-1) words;
//   a WG publishes tag s-1 only after finishing its reads of buf[(s-2)&1]
//   (== buf[s&1]) — so no reader still needs what P overwrites. 0xAA poison
//   gives tag 0xAAAA which never matches (s < 8192): no init required.
__global__ __launch_bounds__(512, 2) void lstm_layer(
    const float* __restrict__ whh_f, const float* __restrict__ whh_b,
    const uint16_t* __restrict__ xg_f, const uint16_t* __restrict__ xg_b,
    uint32_t* hpub_f, uint32_t* hpub_b, uint16_t* __restrict__ hseq) {
  const int bid = blockIdx.x;
  const int dir = bid & 1;
  const int g   = bid >> 1;      // 0..63
  const int hb  = g * 16;
  const int tid = threadIdx.x;
  const int jj  = tid & 15;      // h-index within slice
  const int kc  = tid >> 4;      // k-chunk (32 elems), 0..31
  const int lane = tid & 63;
  const int wv   = tid >> 6;     // wave 0..7

  const float*    whh  = dir ? whh_b : whh_f;
  const uint16_t* xg   = dir ? xg_b : xg_f;
  uint32_t*       hpub = dir ? hpub_b : hpub_f;
  const int colbase    = dir ? H_DIM : 0;

  __shared__ __align__(16) float h_lds[H_DIM];
  __shared__ __align__(16) float part2[8][16][4];

  // W slice: Wr[q][i] = W_hh[q*1024 + hb + jj][kc*32 + i]  (128 f32/thread)
  float Wr[4][32];
#pragma unroll
  for (int q = 0; q < 4; ++q) {
    const float4* wrow = (const float4*)(whh + (size_t)(q * H_DIM + hb + jj) * H_DIM + kc * 32);
#pragma unroll
    for (int i4 = 0; i4 < 8; ++i4) {
      float4 v = wrow[i4];
      Wr[q][i4 * 4 + 0] = v.x; Wr[q][i4 * 4 + 1] = v.y;
      Wr[q][i4 * 4 + 2] = v.z; Wr[q][i4 * 4 + 3] = v.w;
    }
  }

  float cstate = 0.0f;  // threads 0..15 hold c for h-index hb+tid

  for (int s = 0; s < T_SEQ; ++s) {
    const int t = dir ? (T_SEQ - 1 - s) : s;

    float xgv = 0.0f;
    if (tid < 64) xgv = bf2f(xg[(size_t)t * FH + g * 64 + tid]);  // 1 line/WG

    if (s == 0) {
      ((float2*)h_lds)[tid] = make_float2(0.f, 0.f);
    } else {
      const uint64_t etag = ((uint64_t)(uint32_t)((s - 1) << 16) << 32) |
                            (uint32_t)((s - 1) << 16);
      unsigned long long* hp =
          (unsigned long long*)(hpub + (((s - 1) & 1) ? H_DIM : 0)) + tid;
      unsigned long long v;
      for (;;) {
        v = __hip_atomic_load(hp, __ATOMIC_RELAXED, __HIP_MEMORY_SCOPE_AGENT);
        if ((((unsigned long long)v ^ etag) & 0xFFFF0000FFFF0000ull) == 0) break;
        __builtin_amdgcn_s_sleep(1);
      }
      h_lds[2 * tid]     = bf2f((uint32_t)v & 0xFFFFu);
      h_lds[2 * tid + 1] = bf2f((uint32_t)(v >> 32) & 0xFFFFu);
    }
    __syncthreads();  // h_lds ready

    // dot: 4 gate rows over this thread's 32-wide k-chunk
    float a0 = 0.f, a1 = 0.f, a2 = 0.f, a3 = 0.f;
#pragma unroll
    for (int ii = 0; ii < 8; ++ii) {
      float4 h4 = ((const float4*)h_lds)[kc * 8 + ii];
      a0 += Wr[0][ii * 4 + 0] * h4.x; a0 += Wr[0][ii * 4 + 1] * h4.y;
      a0 += Wr[0][ii * 4 + 2] * h4.z; a0 += Wr[0][ii * 4 + 3] * h4.w;
      a1 += Wr[1][ii * 4 + 0] * h4.x; a1 += Wr[1][ii * 4 + 1] * h4.y;
      a1 += Wr[1][ii * 4 + 2] * h4.z; a1 += Wr[1][ii * 4 + 3] * h4.w;
      a2 += Wr[2][ii * 4 + 0] * h4.x; a2 += Wr[2][ii * 4 + 1] * h4.y;
      a2 += Wr[2][ii * 4 + 2] * h4.z; a2 += Wr[2][ii * 4 + 3] * h4.w;
      a3 += Wr[3][ii * 4 + 0] * h4.x; a3 += Wr[3][ii * 4 + 1] * h4.y;
      a3 += Wr[3][ii * 4 + 2] * h4.z; a3 += Wr[3][ii * 4 + 3] * h4.w;
    }
    // reduce over the wave's 4 k-chunks (lanes differing in bits 4,5)
    a0 += __shfl_xor(a0, 16); a1 += __shfl_xor(a1, 16);
    a2 += __shfl_xor(a2, 16); a3 += __shfl_xor(a3, 16);
    a0 += __shfl_xor(a0, 32); a1 += __shfl_xor(a1, 32);
    a2 += __shfl_xor(a2, 32); a3 += __shfl_xor(a3, 32);
    if (lane < 16)
      *(float4*)&part2[wv][lane][0] = make_float4(a0, a1, a2, a3);
    __syncthreads();  // part2 ready

    if (tid < 64) {
      const int gq = tid >> 4, gjj = tid & 15;
      float gval = part2[0][gjj][gq] + part2[1][gjj][gq] +
                   part2[2][gjj][gq] + part2[3][gjj][gq] +
                   part2[4][gjj][gq] + part2[5][gjj][gq] +
                   part2[6][gjj][gq] + part2[7][gjj][gq] + xgv;
      // gather 4 gates of h-index gjj (lanes gjj, +16, +32, +48 of wave 0)
      float gi = gval;
      float gf = __shfl(gval, gjj + 16);
      float gg = __shfl(gval, gjj + 32);
      float go = __shfl(gval, gjj + 48);
      if (gq == 0) {
        float i_s = fsig(gi), f_s = fsig(gf), g_t = ftanh(gg), o_s = fsig(go);
        cstate = f_s * cstate + i_s * g_t;
        float h = o_s * ftanh(cstate);
        uint32_t w = ((uint32_t)s << 16) | f2bf(h);
        __hip_atomic_store(&hpub[(s & 1) * H_DIM + hb + gjj], w,
                           __ATOMIC_RELAXED, __HIP_MEMORY_SCOPE_AGENT);
        hseq[(size_t)t * H2 + colbase + hb + gjj] = (uint16_t)(w & 0xFFFFu);
      }
    }
    // no trailing barrier: next-step h_lds/part2 writes are gated by the poll,
    // which requires this WG's own tag-s publish (after all LDS reads above).
  }
}

// ---------------------------------------------------------------- feats
// feats[t][l] = h1[t,:] . w_out[l,:] + b_out[l];  one wave per row.
__global__ __launch_bounds__(256) void feats_kernel(const uint16_t* __restrict__ h1,
                                                    const float* __restrict__ wout,
                                                    const float* __restrict__ bout,
                                                    float* __restrict__ feats) {
  const int lane = threadIdx.x & 63;
  const int wid  = (blockIdx.x * blockDim.x + threadIdx.x) >> 6;
  const int nwaves = (gridDim.x * blockDim.x) >> 6;

  float wreg[5][32];
#pragma unroll
  for (int j = 0; j < 5; ++j) {
    const float4* src = (const float4*)(wout + j * H2 + lane * 32);
#pragma unroll
    for (int u = 0; u < 8; ++u) {
      float4 v = src[u];
      wreg[j][u * 4 + 0] = v.x; wreg[j][u * 4 + 1] = v.y;
      wreg[j][u * 4 + 2] = v.z; wreg[j][u * 4 + 3] = v.w;
    }
  }
  for (int t = wid; t < T_SEQ; t += nwaves) {
    const uint32_t* hrow = (const uint32_t*)(h1 + (size_t)t * H2) + lane * 16;
    float acc[5] = {0.f, 0.f, 0.f, 0.f, 0.f};
#pragma unroll
    for (int u = 0; u < 16; ++u) {
      uint32_t w2 = hrow[u];
      float hlo = __uint_as_float(w2 << 16);
      float hhi = __uint_as_float(w2 & 0xFFFF0000u);
#pragma unroll
      for (int j = 0; j < 5; ++j)
        acc[j] += wreg[j][u * 2] * hlo + wreg[j][u * 2 + 1] * hhi;
    }
#pragma unroll
    for (int off = 32; off >= 1; off >>= 1)
#pragma unroll
      for (int j = 0; j < 5; ++j)
        acc[j] += __shfl_xor(acc[j], off);
    if (lane < 5) feats[t * NLAB + lane] = acc[lane] + bout[lane];
  }
}

// ---------------------------------------------------------------- Viterbi
// Parallel max-plus scan (chunks of 32 per thread), bps in LDS, pointer-jump backtrack.
__global__ __launch_bounds__(256) void viterbi_kernel(const float* __restrict__ feats,
                                                      const float* __restrict__ trans,
                                                      float* __restrict__ out) {
  __shared__ float scanM[256][26];
  __shared__ uint16_t bpsL[T_SEQ];
  __shared__ int bestL;
  const int tid = threadIdx.x;

  float tr[5][5];
#pragma unroll
  for (int n = 0; n < 5; ++n)
#pragma unroll
    for (int p = 0; p < 5; ++p) tr[n][p] = trans[n * 5 + p];

  // phase 1: per-thread chunk composite
  float C[5][5];
  {
    const int t0 = tid * 32;
    const float* f = feats + (size_t)t0 * 5;
#pragma unroll
    for (int n = 0; n < 5; ++n)
#pragma unroll
      for (int p = 0; p < 5; ++p) C[n][p] = tr[n][p] + f[n];
    for (int t = 1; t < 32; ++t) {
      const float* ft = feats + (size_t)(t0 + t) * 5;
      float Nw[5][5];
#pragma unroll
      for (int n = 0; n < 5; ++n) {
#pragma unroll
        for (int p = 0; p < 5; ++p) {
          float m = tr[n][0] + C[0][p];
#pragma unroll
          for (int k = 1; k < 5; ++k) m = fmaxf(m, tr[n][k] + C[k][p]);
          Nw[n][p] = m + ft[n];
        }
      }
#pragma unroll
      for (int n = 0; n < 5; ++n)
#pragma unroll
        for (int p = 0; p < 5; ++p) C[n][p] = Nw[n][p];
    }
#pragma unroll
    for (int n = 0; n < 5; ++n)
#pragma unroll
      for (int p = 0; p < 5; ++p) scanM[tid][n * 5 + p] = C[n][p];
  }
  __syncthreads();

  // phase 2: Hillis-Steele inclusive scan
  for (int d = 1; d < 256; d <<= 1) {
    float A[5][5], B[5][5];
    const bool has = (tid >= d);
#pragma unroll
    for (int n = 0; n < 5; ++n)
#pragma unroll
      for (int p = 0; p < 5; ++p) A[n][p] = scanM[tid][n * 5 + p];
    if (has) {
#pragma unroll
      for (int n = 0; n < 5; ++n)
#pragma unroll
        for (int p = 0; p < 5; ++p) B[n][p] = scanM[tid - d][n * 5 + p];
    }
    __syncthreads();
    if (has) {
#pragma unroll
      for (int n = 0; n < 5; ++n) {
#pragma unroll
        for (int p = 0; p < 5; ++p) {
          float m = A[n][0] + B[0][p];
#pragma unroll
          for (int k = 1; k < 5; ++k) m = fmaxf(m, A[n][k] + B[k][p]);
          scanM[tid][n * 5 + p] = m;
        }
      }
    }
    __syncthreads();
  }

  // base vector for this chunk
  float fv[5];
  if (tid == 0) {
#pragma unroll
    for (int n = 0; n < 5; ++n) fv[n] = (n == 3) ? 0.0f : NEGV;
  } else {
#pragma unroll
    for (int n = 0; n < 5; ++n) {
      float m = scanM[tid - 1][n * 5 + 3];
#pragma unroll
      for (int p = 0; p < 5; ++p)
        if (p != 3) m = fmaxf(m, scanM[tid - 1][n * 5 + p] + NEGV);
      fv[n] = m;
    }
  }

  // phase 3: exact sequential within chunk; emit backpointers
  {
    const int t0 = tid * 32;
    for (int t = 0; t < 32; ++t) {
      const float* ft = feats + (size_t)(t0 + t) * 5;
      float nf[5];
      uint32_t bits = 0;
#pragma unroll
      for (int n = 0; n < 5; ++n) {
        float m = tr[n][0] + fv[0];
        int arg = 0;
#pragma unroll
        for (int p = 1; p < 5; ++p) {
          float s2 = tr[n][p] + fv[p];
          if (s2 > m) { m = s2; arg = p; }
        }
        nf[n] = m + ft[n];
        bits |= (uint32_t)arg << (3 * n);
      }
      bpsL[t0 + t] = (uint16_t)bits;
#pragma unroll
      for (int n = 0; n < 5; ++n) fv[n] = nf[n];
    }
    if (tid == 255) {
      float m = fv[0] + tr[4][0];
      int arg = 0;
#pragma unroll
      for (int p = 1; p < 5; ++p) {
        float s2 = fv[p] + tr[4][p];
        if (s2 > m) { m = s2; arg = p; }
      }
      out[0] = m;       // score
      bestL = arg;
    }
  }
  __syncthreads();

  // phase 4: pointer-jump suffix composition
  for (int d = 1; d < T_SEQ; d <<= 1) {
    uint32_t own[32], par[32];
#pragma unroll
    for (int k = 0; k < 32; ++k) {
      int t = tid + k * 256;
      own[k] = bpsL[t];
      par[k] = (t + d < T_SEQ) ? (uint32_t)bpsL[t + d] : 0u;
    }
    __syncthreads();
#pragma unroll
    for (int k = 0; k < 32; ++k) {
      int t = tid + k * 256;
      if (t + d < T_SEQ) {
        uint32_t fmp = own[k], gmp = par[k], r = 0;
#pragma unroll
        for (int x = 0; x < 5; ++x) {
          uint32_t j = (gmp >> (3 * x)) & 7u;
          uint32_t v = (fmp >> (3 * j)) & 7u;
          r |= v << (3 * x);
        }
        bpsL[t] = (uint16_t)r;
      }
    }
    __syncthreads();
  }

  const int best = bestL;
  for (int k = 0; k < 32; ++k) {
    int t = tid + k * 256;
    int lbl = (t == T_SEQ - 1) ? best : (int)((bpsL[t + 1] >> (3 * best)) & 7u);
    out[1 + t] = (float)lbl;
  }
}

// ---------------------------------------------------------------- launcher
extern "C" void kernel_launch(void* const* d_in, const int* in_sizes, int n_in,
                              void* d_out, int out_size, void* d_ws, size_t ws_size,
                              hipStream_t stream) {
  const float* hours     = (const float*)d_in[0];
  const float* w_ih_l0   = (const float*)d_in[1];
  const float* w_hh_l0   = (const float*)d_in[2];
  const float* b_ih_l0   = (const float*)d_in[3];
  const float* b_hh_l0   = (const float*)d_in[4];
  const float* w_ih_l0r  = (const float*)d_in[5];
  const float* w_hh_l0r  = (const float*)d_in[6];
  const float* b_ih_l0r  = (const float*)d_in[7];
  const float* b_hh_l0r  = (const float*)d_in[8];
  const float* w_ih_l1   = (const float*)d_in[9];
  const float* w_hh_l1   = (const float*)d_in[10];
  const float* b_ih_l1   = (const float*)d_in[11];
  const float* b_hh_l1   = (const float*)d_in[12];
  const float* w_ih_l1r  = (const float*)d_in[13];
  const float* w_hh_l1r  = (const float*)d_in[14];
  const float* b_ih_l1r  = (const float*)d_in[15];
  const float* b_hh_l1r  = (const float*)d_in[16];
  const float* w_out     = (const float*)d_in[17];
  const float* b_out     = (const float*)d_in[18];
  const float* transitions = (const float*)d_in[19];
  float* out = (float*)d_out;

  // ws layout (peak ~160.6 MB): h1seq aliases h0seq (h0 is dead once the
  // layer-1 gemms have consumed it; layer-1 lstm reads only xgf/xgb).
  char* ws = (char*)d_ws;
  size_t off = 0;
  auto alloc = [&](size_t bytes) -> void* {
    void* p = ws + off;
    off += (bytes + 255) & ~(size_t)255;
    return p;
  };
  uint16_t* xgf   = (uint16_t*)alloc((size_t)T_SEQ * FH * 2);   // 64 MB (reused for layer 1)
  uint16_t* xgb   = (uint16_t*)alloc((size_t)T_SEQ * FH * 2);   // 64 MB
  uint16_t* h0seq = (uint16_t*)alloc((size_t)T_SEQ * H2 * 2);   // 32 MB (h1seq aliases)
  uint16_t* h1seq = h0seq;
  float*    bsum  = (float*)alloc((size_t)4 * FH * 4);
  uint32_t* hpub  = (uint32_t*)alloc((size_t)2 * 2 * 2 * H_DIM * 4); // layer x dir x parity
  float*    feats = (float*)alloc((size_t)T_SEQ * NLAB * 4);
  (void)ws_size; (void)in_sizes; (void)n_in; (void)out_size;

  bias_kernel<<<64, 256, 0, stream>>>(b_ih_l0, b_hh_l0, b_ih_l0r, b_hh_l0r,
                                      b_ih_l1, b_hh_l1, b_ih_l1r, b_hh_l1r, bsum);
  dim3 gg(64, 32);
  gemm_xg<true><<<gg, 256, 0, stream>>>(hours, w_ih_l0,  bsum + 0 * FH, xgf, E_IN);
  gemm_xg<true><<<gg, 256, 0, stream>>>(hours, w_ih_l0r, bsum + 1 * FH, xgb, E_IN);
  lstm_layer<<<128, 512, 0, stream>>>(w_hh_l0, w_hh_l0r, xgf, xgb,
                                      hpub + 0, hpub + 2048, h0seq);
  gemm_xg<false><<<gg, 256, 0, stream>>>(h0seq, w_ih_l1,  bsum + 2 * FH, xgf, H2);
  gemm_xg<false><<<gg, 256, 0, stream>>>(h0seq, w_ih_l1r, bsum + 3 * FH, xgb, H2);
  lstm_layer<<<128, 512, 0, stream>>>(w_hh_l1, w_hh_l1r, xgf, xgb,
                                      hpub + 4096, hpub + 6144, h1seq);
  feats_kernel<<<128, 256, 0, stream>>>(h1seq, w_out, b_out, feats);
  viterbi_kernel<<<1, 256, 0, stream>>>(feats, transitions, out);
}